// Round 5
// baseline (283.709 us; speedup 1.0000x reference)
//
#include <hip/hip_runtime.h>
#include <hip/hip_bf16.h>

// Problem constants
#define NB 8
#define NC 512
#define HW 4096
#define INNER 32

typedef unsigned short u16;
typedef unsigned int u32;
typedef __attribute__((ext_vector_type(8))) short bf16x8;   // 8 bf16 = 4 VGPRs
typedef __attribute__((ext_vector_type(4))) float f32x4;    // MFMA C/D

__device__ __forceinline__ float b2f(u16 u) {
    union { u32 a; float f; } z;
    z.a = ((u32)u) << 16;
    return z.f;
}

// fp32 -> bf16 with round-to-nearest-even
__device__ __forceinline__ u16 f2b(float v) {
    u32 x = __float_as_uint(v);
    return (u16)((x + 0x7fffu + ((x >> 16) & 1u)) >> 16);
}

// Dtype-flexible input load. isf32: 1 = fp32 tensors, 0 = bf16 tensors.
__device__ __forceinline__ float ldin(const void* p, int idx, int isf32) {
    if (isf32) return ((const float*)p)[idx];
    return b2f(((const u16*)p)[idx]);
}

// async global->LDS, 16 B per lane, dest = wave-uniform base + lane*16
__device__ __forceinline__ void gld_lds16(const void* g, void* l) {
    __builtin_amdgcn_global_load_lds(
        (const __attribute__((address_space(1))) unsigned int*)g,
        (__attribute__((address_space(3))) unsigned int*)l, 16, 0, 0);
}

// Resolve input dtype. hisf >= 0: trusted host answer (from exact in_sizes
// match). Otherwise: wave-level bit-pattern ballot on `content`.
__device__ __forceinline__ int resolve_isf32(int hisf, const void* content) {
    if (hisf >= 0) return hisf;
    int lane = threadIdx.x & 63;
    u16 u = ((const u16*)content)[lane * 2048];
    int e = (u >> 7) & 0xff;
    unsigned long long m = __ballot(e >= 100 && e <= 150);
    return (__popcll(m) < 32) ? 1 : 0;
}

// ===========================================================================
// Role bodies (merged-launch building blocks)
// ===========================================================================

// Style stats per (b,c) plane (vectorized) + fused pooled contribution:
// after reducing the 9 shifted window sums, 64 threads dot them with
// cw1/cw2[o,c,:] and atomicAdd into pooled_raw[set,b,o].
__device__ __forceinline__ void role_style(int bc, const void* style,
        const void* cw1, const void* cw2, float* pooled_raw,
        int isf32, float* smf) {
    int b = bc >> 9, c = bc & 511;
    int base = bc * HW;
    int tid = threadIdx.x;
    float t = 0.f, top = 0.f, bot = 0.f, lft = 0.f, rgt = 0.f;
    if (isf32) {
        const float4* sp = (const float4*)((const float*)style + base);
#pragma unroll
        for (int k = 0; k < 4; k++) {
            int q = tid + k * 256;              // float4 idx 0..1023
            float4 v = sp[q];
            float s4 = (v.x + v.y) + (v.z + v.w);
            int h = q >> 4, w0 = (q & 15) * 4;
            t += s4;
            if (h == 0)   top += s4;
            if (h == 63)  bot += s4;
            if (w0 == 0)  lft += v.x;
            if (w0 == 60) rgt += v.w;
        }
    } else {
        const uint4* sp = (const uint4*)((const u16*)style + base);
#pragma unroll
        for (int k = 0; k < 2; k++) {
            int q = tid + k * 256;              // 8-elem idx 0..511
            uint4 v = sp[q];
            float e0 = b2f((u16)(v.x & 0xffffu)), e1 = b2f((u16)(v.x >> 16));
            float e2 = b2f((u16)(v.y & 0xffffu)), e3 = b2f((u16)(v.y >> 16));
            float e4 = b2f((u16)(v.z & 0xffffu)), e5 = b2f((u16)(v.z >> 16));
            float e6 = b2f((u16)(v.w & 0xffffu)), e7 = b2f((u16)(v.w >> 16));
            float s8 = ((e0 + e1) + (e2 + e3)) + ((e4 + e5) + (e6 + e7));
            int h = q >> 3, w0 = (q & 7) * 8;
            t += s8;
            if (h == 0)   top += s8;
            if (h == 63)  bot += s8;
            if (w0 == 0)  lft += e0;
            if (w0 == 56) rgt += e7;
        }
    }
#pragma unroll
    for (int off = 32; off > 0; off >>= 1) {
        t   += __shfl_down(t, off);
        top += __shfl_down(top, off);
        bot += __shfl_down(bot, off);
        lft += __shfl_down(lft, off);
        rgt += __shfl_down(rgt, off);
    }
    int wave = tid >> 6;
    if ((tid & 63) == 0) {
        smf[20 + wave * 5 + 0] = t;   smf[20 + wave * 5 + 1] = top;
        smf[20 + wave * 5 + 2] = bot; smf[20 + wave * 5 + 3] = lft;
        smf[20 + wave * 5 + 4] = rgt;
    }
    __syncthreads();
    if (tid == 0) {
        t   = smf[20] + smf[25] + smf[30] + smf[35];
        top = smf[21] + smf[26] + smf[31] + smf[36];
        bot = smf[22] + smf[27] + smf[32] + smf[37];
        lft = smf[23] + smf[28] + smf[33] + smf[38];
        rgt = smf[24] + smf[29] + smf[34] + smf[39];
        float c00 = ldin(style, base + 0,    isf32);
        float c0W = ldin(style, base + 63,   isf32);
        float cH0 = ldin(style, base + 4032, isf32);
        float cHW = ldin(style, base + 4095, isf32);
        smf[0] = t - bot - rgt + cHW;
        smf[1] = t - bot;
        smf[2] = t - bot - lft + cH0;
        smf[3] = t - rgt;
        smf[4] = t;
        smf[5] = t - lft;
        smf[6] = t - top - rgt + c0W;
        smf[7] = t - top;
        smf[8] = t - top - lft + c00;
    }
    __syncthreads();
    if (tid < 64) {
        int set = tid >> 5, o = tid & 31;
        const void* cw = set ? cw2 : cw1;
        int wb = (o * NC + c) * 9;
        float acc = 0.f;
#pragma unroll
        for (int k = 0; k < 9; k++) acc += ldin(cw, wb + k, isf32) * smf[k];
        atomicAdd(&pooled_raw[(set * NB + b) * 32 + o], acc);
    }
}

// Transpose content [b][c][h][w] -> cT [(b4*16+ci)][h][w][32] bf16 with the
// c-group XOR swizzle baked in (key (w+1)&3). 2 h-rows per block.
__device__ __forceinline__ void role_transform(int ridx, const void* content,
        u16* cT, int bstart, int isf32, float* lds) {
    int hp = ridx & 31;                 // h-pair: rows 2hp, 2hp+1
    int ci = (ridx >> 5) & 15;
    int b4 = ridx >> 9;
    int tid = threadIdx.x;
    size_t gbase = ((size_t)(bstart + b4) * NC + ci * 32) * HW + (size_t)hp * 128;
    if (isf32) {
#pragma unroll
        for (int r2 = 0; r2 < 2; r2++)
#pragma unroll
            for (int k = 0; k < 2; k++) {
                int q = tid + k * 256;                  // 0..511 float4s
                int c = q >> 4, w0 = (q & 15) * 4;
                float4 v = *(const float4*)((const float*)content
                            + gbase + (size_t)c * HW + r2 * 64 + w0);
                float* dst = lds + r2 * 2080 + c * 65 + w0;
                dst[0] = v.x; dst[1] = v.y; dst[2] = v.z; dst[3] = v.w;
            }
    } else {
#pragma unroll
        for (int r2 = 0; r2 < 2; r2++) {
            int c = tid >> 3, w0 = (tid & 7) * 8;
            uint4 v = *(const uint4*)((const u16*)content
                        + gbase + (size_t)c * HW + r2 * 64 + w0);
            float* dst = lds + r2 * 2080 + c * 65 + w0;
            dst[0] = b2f((u16)(v.x & 0xffffu));
            dst[1] = b2f((u16)(v.x >> 16));
            dst[2] = b2f((u16)(v.y & 0xffffu));
            dst[3] = b2f((u16)(v.y >> 16));
            dst[4] = b2f((u16)(v.z & 0xffffu));
            dst[5] = b2f((u16)(v.z >> 16));
            dst[6] = b2f((u16)(v.w & 0xffffu));
            dst[7] = b2f((u16)(v.w >> 16));
        }
    }
    __syncthreads();
#pragma unroll
    for (int r2 = 0; r2 < 2; r2++) {
        u32* out = (u32*)(cT + ((size_t)(b4 * 16 + ci) * 4096
                                + (hp * 2 + r2) * 64) * 32);
        const float* src = lds + r2 * 2080;
#pragma unroll
        for (int k = 0; k < 4; k++) {
            int j = tid + k * 256;          // 0..1023 u32 slots
            int w = j >> 4, cpair = j & 15;
            int key = (w + 1) & 3;
            int p0 = cpair << 1;
            int lc = (((p0 >> 3) ^ key) << 3) | (p0 & 7);
            out[j] = (u32)f2b(src[lc * 65 + w])
                   | ((u32)f2b(src[(lc + 1) * 65 + w]) << 16);
        }
    }
}

// Pack ds_w [32][512][3][3] -> MFMA B-fragments (bf16).
__device__ __forceinline__ void role_prep_wdown(int ridx, const void* dsw,
        u16* Bp, int isf32) {
    int idx = ridx * 256 + threadIdx.x;             // < 147456
    int e = idx & 7, l = (idx >> 3) & 63, nf = (idx >> 9) & 1;
    int cb = (idx >> 10) & 15, t9 = idx >> 14;
    int oc = nf * 16 + (l & 15);
    int c = cb * 32 + (l >> 4) * 8 + e;
    Bp[idx] = f2b(ldin(dsw, (oc * NC + c) * 9 + t9, isf32));
}

// Pack up_w [512][32][3][3] -> B2_pack.
__device__ __forceinline__ void role_prep_wup(int ridx, const void* upw,
        u16* B2p, int isf32) {
    int idx = ridx * 256 + threadIdx.x;             // < 147456
    int e = idx & 7, l = (idx >> 3) & 63, nfo = (idx >> 9) & 31, t9 = idx >> 14;
    int oc = nfo * 16 + (l & 15);
    int ic = (l >> 4) * 8 + e;
    B2p[idx] = f2b(ldin(upw, (oc * INNER + ic) * 9 + t9, isf32));
}

// FC: f[b,row] = pooled[b,:]·fw[row,:] + fb[row]; written as MFMA B-frags.
// pooled[b,o] = pooled_raw*(1/4096) + conv-bias, applied at read.
__device__ __forceinline__ void role_fc(int ridx, const float* pooled_raw,
        const void* cbf1, const void* cbf2,
        const void* fw1, const void* fb1, const void* fw2, const void* fb2,
        u16* fpack, int isf32, float* p) {
    int set = ridx / 288;
    int rr = ridx - set * 288;
    int b = rr / 36;
    int chunk = rr - b * 36;
    int row = chunk * 256 + threadIdx.x;       // 0..9215
    const void* fw = set ? fw2 : fw1;
    const void* fb = set ? fb2 : fb1;
    if (threadIdx.x < 32)
        p[threadIdx.x] = pooled_raw[(set * NB + b) * 32 + threadIdx.x]
                           * (1.0f / 4096.0f)
                       + ldin(set ? cbf2 : cbf1, threadIdx.x, isf32);
    __syncthreads();
    float acc = ldin(fb, row, isf32);
    if (isf32) {
        const float* fwf = (const float*)fw + row * 32;
#pragma unroll
        for (int j = 0; j < 32; j++) acc += fwf[j] * p[j];
    } else {
        const u32* w32 = (const u32*)((const u16*)fw + row * 32);
#pragma unroll
        for (int j = 0; j < 16; j++) {
            u32 u = w32[j];
            acc += b2f((u16)(u & 0xffffu)) * p[2 * j];
            acc += b2f((u16)(u >> 16)) * p[2 * j + 1];
        }
    }
    int oc = row / 288;
    int rem = row - oc * 288;
    int ic = rem / 9;
    int t9 = rem - ic * 9;
    int l = (oc & 15) | ((ic >> 3) << 4);
    int e = ic & 7;
    int nf = oc >> 4;
    fpack[((((set * NB + b) * 9 + t9) * 2 + nf) * 64 + l) * 8 + e] = f2b(acc);
}

// Conv 512->32 MFMA implicit GEMM, reading pre-transposed+swizzled cT.
__device__ __forceinline__ void role_conv_down(int x, const u16* cT,
        const u16* Bp, const void* dsb, u16* c0T, int bstart, int isf32,
        u16* lds) {
    u32* lds32 = (u32*)lds;
    int b4 = x >> 6, row = x & 63;
    int b = bstart + b4;
    int tid = threadIdx.x, lane = tid & 63;
    int wid = __builtin_amdgcn_readfirstlane(tid >> 6);
    // zero everything once: halo cols + out-of-range rows stay zero forever
    for (int i = tid; i < 3 * 66 * 16; i += 256) lds32[i] = 0u;
    __syncthreads();

    int m = lane & 15, g = lane >> 4;
    int wbase = wid * 16;
    f32x4 acc0 = {0.f, 0.f, 0.f, 0.f}, acc1 = {0.f, 0.f, 0.f, 0.f};

    for (int ci = 0; ci < 16; ci++) {
        if (ci) __syncthreads();
        const u16* sp = cT + ((size_t)(b4 * 16 + ci) * 4096) * 32;
#pragma unroll
        for (int r = 0; r < 3; r++) {
            int gh = row + r - 1;
            if (gh >= 0 && gh < 64)
                gld_lds16(sp + (size_t)gh * 2048 + tid * 8,
                          (char*)lds + (r * 66 + 1) * 64 + wid * 1024);
        }
        __syncthreads();
#pragma unroll
        for (int t9 = 0; t9 < 9; t9++) {
            int dh = t9 / 3, dw = t9 - dh * 3;
            int wi = wbase + m + dw;
            bf16x8 a = *(const bf16x8*)(lds + ((dh * 66 + wi) * 32 + ((g ^ (wi & 3)) * 8)));
            bf16x8 b0 = ((const bf16x8*)Bp)[((t9 * 16 + ci) * 2 + 0) * 64 + lane];
            bf16x8 b1 = ((const bf16x8*)Bp)[((t9 * 16 + ci) * 2 + 1) * 64 + lane];
            acc0 = __builtin_amdgcn_mfma_f32_16x16x32_bf16(a, b0, acc0, 0, 0, 0);
            acc1 = __builtin_amdgcn_mfma_f32_16x16x32_bf16(a, b1, acc1, 0, 0, 0);
        }
    }
    float bia0 = ldin(dsb, m, isf32);
    float bia1 = ldin(dsb, 16 + m, isf32);
    size_t obase = ((size_t)b * 4096 + row * 64) * 32;
    int pix0 = wbase + g * 4;
#pragma unroll
    for (int r = 0; r < 4; r++) {
        int w = pix0 + r;
        int key = (w + 1) & 3;
        int p0 = (((m >> 3) ^ key) << 3) | (m & 7);
        int p1 = ((((16 + m) >> 3) ^ key) << 3) | (m & 7);
        c0T[obase + (size_t)w * 32 + p0] = f2b(acc0[r] + bia0);
        c0T[obase + (size_t)w * 32 + p1] = f2b(acc1[r] + bia1);
    }
}

// ===========================================================================
// Merged launches
// ===========================================================================

// Front: style_stats(+pooled) | transform | prep_wdown | prep_wup
__global__ __launch_bounds__(256) void k_front(
        const void* __restrict__ style,
        const void* __restrict__ cw1, const void* __restrict__ cw2,
        float* __restrict__ pooled_raw, int nStyle,
        const void* __restrict__ content, u16* __restrict__ cT, int bstart, int nT,
        const void* __restrict__ dsw, u16* __restrict__ Bp,
        const void* __restrict__ upw, u16* __restrict__ B2p, int nPrep,
        int hisf) {
    __shared__ float smf[2 * 2080];     // transform: 2 rows; style: 40 floats
    int isf32 = resolve_isf32(hisf, content);
    int x = blockIdx.x;
    if (x < nStyle) { role_style(x, style, cw1, cw2, pooled_raw, isf32, smf); return; }
    x -= nStyle;
    if (x < nT) { role_transform(x, content, cT, bstart, isf32, smf); return; }
    x -= nT;
    if (x < nPrep) { role_prep_wdown(x, dsw, Bp, isf32); return; }
    x -= nPrep;
    role_prep_wup(x, upw, B2p, isf32);
}

// Mid: conv_down | fc
__global__ __launch_bounds__(256) void k_mid(
        const u16* __restrict__ cT, const u16* __restrict__ Bp,
        const void* __restrict__ dsb, u16* __restrict__ c0T, int bstart, int nCD,
        const float* __restrict__ pooled_raw,
        const void* __restrict__ cbf1, const void* __restrict__ cbf2,
        const void* __restrict__ fw1, const void* __restrict__ fb1,
        const void* __restrict__ fw2, const void* __restrict__ fb2,
        u16* __restrict__ fpack, const void* __restrict__ content, int hisf) {
    __shared__ u16 lds[3 * 66 * 32];
    int isf32 = resolve_isf32(hisf, content);
    int x = blockIdx.x;
    if (x < nCD) { role_conv_down(x, cT, Bp, dsb, c0T, bstart, isf32, lds); return; }
    role_fc(x - nCD, pooled_raw, cbf1, cbf2, fw1, fb1, fw2, fb2, fpack,
            isf32, (float*)lds);
}

// ---------------------------------------------------------------------------
// Per-sample dynamic 32->32 conv (MFMA) + optional LeakyReLU.
// srcT/dstT: [b][h][w][32] bf16, swizzled (key (w+1)&3). Staged linear.
// ---------------------------------------------------------------------------
__global__ __launch_bounds__(256) void k_apply(const u16* __restrict__ srcT,
        const u16* __restrict__ fpack, u16* __restrict__ dstT, int lrelu) {
    int b = blockIdx.x >> 6, row = blockIdx.x & 63;
    int tid = threadIdx.x, lane = tid & 63;
    int wid = __builtin_amdgcn_readfirstlane(tid >> 6);
    __shared__ u16 lds[3 * 66 * 32];
    u32* lds32 = (u32*)lds;
    for (int i = tid; i < 96; i += 256) {
        int r = i >> 5, side = (i >> 4) & 1, cpr = i & 15;
        lds32[(r * 66 + side * 65) * 16 + cpr] = 0u;
    }
    const u16* sp = srcT + (size_t)b * 64 * 64 * 32;
    for (int r = 0; r < 3; r++) {
        int gh = row + r - 1;
        u32 ldsoff = (u32)(r * 66 + 1) * 64 + (u32)wid * 1024;  // bytes
        if (gh >= 0 && gh < 64) {
            gld_lds16(sp + (size_t)gh * 2048 + tid * 8, (char*)lds + ldsoff);
        } else {
            int4 z = make_int4(0, 0, 0, 0);
            *(int4*)((char*)lds + ldsoff + (u32)lane * 16) = z;
        }
    }
    __syncthreads();

    int m = lane & 15, g = lane >> 4, wbase = wid * 16;
    f32x4 acc0 = {0.f, 0.f, 0.f, 0.f}, acc1 = {0.f, 0.f, 0.f, 0.f};
    const bf16x8* FB = (const bf16x8*)fpack + (size_t)b * 1152;
#pragma unroll
    for (int t9 = 0; t9 < 9; t9++) {
        int dh = t9 / 3, dw = t9 - dh * 3;
        int wi = wbase + m + dw;
        bf16x8 a = *(const bf16x8*)(lds + ((dh * 66 + wi) * 32 + ((g ^ (wi & 3)) * 8)));
        bf16x8 b0 = FB[(t9 * 2 + 0) * 64 + lane];
        bf16x8 b1 = FB[(t9 * 2 + 1) * 64 + lane];
        acc0 = __builtin_amdgcn_mfma_f32_16x16x32_bf16(a, b0, acc0, 0, 0, 0);
        acc1 = __builtin_amdgcn_mfma_f32_16x16x32_bf16(a, b1, acc1, 0, 0, 0);
    }
    size_t obase = ((size_t)(b * 64 + row) * 64) * 32;
    int pix0 = wbase + g * 4;
#pragma unroll
    for (int r = 0; r < 4; r++) {
        float v0 = acc0[r], v1 = acc1[r];
        if (lrelu) {
            v0 = (v0 >= 0.f) ? v0 : 0.2f * v0;
            v1 = (v1 >= 0.f) ? v1 : 0.2f * v1;
        }
        int w = pix0 + r;
        int key = (w + 1) & 3;
        int p0 = (((m >> 3) ^ key) << 3) | (m & 7);
        int p1 = ((((16 + m) >> 3) ^ key) << 3) | (m & 7);
        dstT[obase + (size_t)w * 32 + p0] = f2b(v0);
        dstT[obase + (size_t)w * 32 + p1] = f2b(v1);
    }
}

// ---------------------------------------------------------------------------
// Conv 32->512 (MFMA) + bias + residual -> out. blockIdx.y = oc quarter.
// Epilogue bounced through LDS [oc][px] (stride 68, 2 halves of 64 oc) so
// the residual loads and output stores are 16-lane-contiguous (256 B).
// ---------------------------------------------------------------------------
__global__ __launch_bounds__(256) void k_conv_up(const u16* __restrict__ c2T,
        const u16* __restrict__ B2p, const void* __restrict__ upb,
        const void* __restrict__ content, void* __restrict__ outv, int hisf) {
    int isf32 = resolve_isf32(hisf, content);
    int b = blockIdx.x >> 6, row = blockIdx.x & 63;
    int nq = blockIdx.y;                           // 0..3
    int tid = threadIdx.x, lane = tid & 63;
    int wid = __builtin_amdgcn_readfirstlane(tid >> 6);
    __shared__ char smem[64 * 68 * 4] __attribute__((aligned(16)));  // 17408 B
    u16* lds = (u16*)smem;
    u32* lds32 = (u32*)smem;
    for (int i = tid; i < 96; i += 256) {
        int r = i >> 5, side = (i >> 4) & 1, cpr = i & 15;
        lds32[(r * 66 + side * 65) * 16 + cpr] = 0u;
    }
    const u16* sp = c2T + (size_t)b * 64 * 64 * 32;
    for (int r = 0; r < 3; r++) {
        int gh = row + r - 1;
        u32 ldsoff = (u32)(r * 66 + 1) * 64 + (u32)wid * 1024;
        if (gh >= 0 && gh < 64) {
            gld_lds16(sp + (size_t)gh * 2048 + tid * 8, (char*)lds + ldsoff);
        } else {
            int4 z = make_int4(0, 0, 0, 0);
            *(int4*)((char*)lds + ldsoff + (u32)lane * 16) = z;
        }
    }
    __syncthreads();

    int m = lane & 15, g = lane >> 4, wbase = wid * 16;
    f32x4 acc[8];
#pragma unroll
    for (int i = 0; i < 8; i++) acc[i] = (f32x4){0.f, 0.f, 0.f, 0.f};
#pragma unroll
    for (int t9 = 0; t9 < 9; t9++) {
        int dh = t9 / 3, dw = t9 - dh * 3;
        int wi = wbase + m + dw;
        bf16x8 a = *(const bf16x8*)(lds + ((dh * 66 + wi) * 32 + ((g ^ (wi & 3)) * 8)));
#pragma unroll
        for (int nfl = 0; nfl < 8; nfl++) {
            bf16x8 bw = ((const bf16x8*)B2p)[(t9 * 32 + nq * 8 + nfl) * 64 + lane];
            acc[nfl] = __builtin_amdgcn_mfma_f32_16x16x32_bf16(a, bw, acc[nfl], 0, 0, 0);
        }
    }

    // Coalesced epilogue via LDS: two halves of 64 oc, [ocl][px] stride 68.
    int pix0 = wbase + g * 4;
    float* fl = (float*)smem;
    int ocl2 = tid >> 4;            // 0..15
    int px0 = (tid & 15) * 4;       // 0..60
    __syncthreads();                // input tile dead
#pragma unroll
    for (int hf = 0; hf < 2; hf++) {
        if (hf) __syncthreads();
#pragma unroll
        for (int nf = 0; nf < 4; nf++) {
            int ocl = nf * 16 + m;
            *(f32x4*)(fl + ocl * 68 + pix0) = acc[hf * 4 + nf];
        }
        __syncthreads();
#pragma unroll
        for (int p = 0; p < 4; p++) {
            int ocl = p * 16 + ocl2;
            int oc = nq * 128 + hf * 64 + ocl;
            float bias = ldin(upb, oc, isf32);
            f32x4 v4 = *(const f32x4*)(fl + ocl * 68 + px0);
            size_t idx = ((size_t)b * NC + oc) * HW + (size_t)row * 64 + px0;
            if (isf32) {
                f32x4 rsd = *(const f32x4*)((const float*)content + idx);
                f32x4 ov;
#pragma unroll
                for (int r = 0; r < 4; r++) ov[r] = v4[r] + bias + rsd[r];
                *(f32x4*)((float*)outv + idx) = ov;
            } else {
                ushort4 rv = *(const ushort4*)((const u16*)content + idx);
                ushort4 ov;
                ov.x = f2b(v4[0] + bias + b2f(rv.x));
                ov.y = f2b(v4[1] + bias + b2f(rv.y));
                ov.z = f2b(v4[2] + bias + b2f(rv.z));
                ov.w = f2b(v4[3] + bias + b2f(rv.w));
                *(ushort4*)((u16*)outv + idx) = ov;
            }
        }
    }
}

// ---------------------------------------------------------------------------
extern "C" void kernel_launch(void* const* d_in, const int* in_sizes, int n_in,
                              void* d_out, int out_size, void* d_ws, size_t ws_size,
                              hipStream_t stream) {
    const void* content = d_in[0];
    const void* style   = d_in[1];
    const void* ds_w    = d_in[2];
    const void* ds_b    = d_in[3];
    const void* up_w    = d_in[4];
    const void* up_b    = d_in[5];
    const void* f1_cw   = d_in[6];
    const void* f1_cb   = d_in[7];
    const void* f1_fw   = d_in[8];
    const void* f1_fb   = d_in[9];
    const void* f2_cw   = d_in[10];
    const void* f2_cb   = d_in[11];
    const void* f2_fw   = d_in[12];
    const void* f2_fb   = d_in[13];

    // Host-side dtype resolution from exact input byte sizes; -1 = unknown,
    // kernels fall back to wave-ballot bit detection.
    int hisf = -1;
    if (in_sizes && n_in >= 1) {
        if (in_sizes[0] == NB * NC * HW * 4) hisf = 1;
        else if (in_sizes[0] == NB * NC * HW * 2) hisf = 0;
    }

    const size_t SZ_PACK = 294912;       // 147456 u16
    const size_t SZ_CT2  = 2097152;      // 1,048,576 u16 (32-ch bf16 tensor)
    const size_t REQ_WS  = 3 * SZ_CT2 + 3 * SZ_PACK + 2048 + 64;

    if (ws_size >= REQ_WS) {
        // FULL path: all intermediates in d_ws; d_out holds only cT (full
        // batch, 33,554,432 B <= out_size), dead before k_conv_up writes out.
        char* w = (char*)d_ws;
        u16*   B2pack = (u16*)w;                 w += SZ_PACK;
        u16*   c2T    = (u16*)w;                 w += SZ_CT2;
        u16*   c0T    = (u16*)w;                 w += SZ_CT2;
        u16*   c1T    = (u16*)w;                 w += SZ_CT2;
        u16*   Bpack  = (u16*)w;                 w += SZ_PACK;
        u16*   fpack  = (u16*)w;                 w += SZ_PACK;
        float* pooled_raw = (float*)w;
        u16*   cT     = (u16*)d_out;

        hipMemsetAsync(pooled_raw, 0, 2 * NB * 32 * 4, stream);
        // L1: style(4096) + transform(4096, 2 rows/block) + preps(2x576)
        k_front<<<4096 + 4096 + 2 * 576, 256, 0, stream>>>(
            style, f1_cw, f2_cw, pooled_raw, 4096,
            content, cT, 0, 4096,
            ds_w, Bpack, up_w, B2pack, 576, hisf);
        // L2: conv_down(512) + fc(576)
        k_mid<<<512 + 576, 256, 0, stream>>>(
            cT, Bpack, ds_b, c0T, 0, 512,
            pooled_raw, f1_cb, f2_cb,
            f1_fw, f1_fb, f2_fw, f2_fb, fpack, content, hisf);
        // L3/L4: dynamic convs
        k_apply<<<NB * 64, 256, 0, stream>>>(c0T, fpack, c1T, 1);
        k_apply<<<NB * 64, 256, 0, stream>>>(c1T, fpack + NB * 9216, c2T, 0);
        // L5: conv_up
        k_conv_up<<<dim3(NB * 64, 4), 256, 0, stream>>>(c2T, B2pack, up_b,
                                                        content, d_out, hisf);
    } else {
        // HALF path (small ws): scratch in d_out, cT half-batch reused.
        float* pooled_raw = (float*)d_out;           //       512 f32
        u16*   fpack  = (u16*)(pooled_raw + 512);    //   147,456 u16
        u16*   Bpack  = fpack + 147456;              //   147,456 u16
        u16*   c0T    = Bpack + 147456;              // 1,048,576 u16
        u16*   c1T    = c0T + 1048576;               // 1,048,576 u16
        u16*   cTh    = c1T + 1048576;               // 8,388,608 u16
        u16*   B2pack = (u16*)d_ws;                  //   147,456 u16
        u16*   c2T    = B2pack + 147456;             // 1,048,576 u16

        hipMemsetAsync(pooled_raw, 0, 2 * NB * 32 * 4, stream);
        // L1: style + transform(half0, 2048) + preps
        k_front<<<4096 + 2048 + 2 * 576, 256, 0, stream>>>(
            style, f1_cw, f2_cw, pooled_raw, 4096,
            content, cTh, 0, 2048,
            ds_w, Bpack, up_w, B2pack, 576, hisf);
        // L2: conv_down(half0) + fc(576)
        k_mid<<<256 + 576, 256, 0, stream>>>(
            cTh, Bpack, ds_b, c0T, 0, 256,
            pooled_raw, f1_cb, f2_cb,
            f1_fw, f1_fb, f2_fw, f2_fb, fpack, content, hisf);
        // L3: transform(half1)
        k_front<<<2048, 256, 0, stream>>>(
            style, f1_cw, f2_cw, pooled_raw, 0,
            content, cTh, 4, 2048,
            ds_w, Bpack, up_w, B2pack, 0, hisf);
        // L4: conv_down(half1)
        k_mid<<<256, 256, 0, stream>>>(
            cTh, Bpack, ds_b, c0T, 4, 256,
            pooled_raw, f1_cb, f2_cb,
            f1_fw, f1_fb, f2_fw, f2_fb, fpack, content, hisf);
        // L5/L6: dynamic convs
        k_apply<<<NB * 64, 256, 0, stream>>>(c0T, fpack, c1T, 1);
        k_apply<<<NB * 64, 256, 0, stream>>>(c1T, fpack + NB * 9216, c2T, 0);
        // L7: conv_up
        k_conv_up<<<dim3(NB * 64, 4), 256, 0, stream>>>(c2T, B2pack, up_b,
                                                        content, d_out, hisf);
    }
}

// Round 6
// 282.337 us; speedup vs baseline: 1.0049x; 1.0049x over previous
//
#include <hip/hip_runtime.h>
#include <hip/hip_bf16.h>

// Problem constants
#define NB 8
#define NC 512
#define HW 4096
#define INNER 32

typedef unsigned short u16;
typedef unsigned int u32;
typedef __attribute__((ext_vector_type(8))) short bf16x8;   // 8 bf16 = 4 VGPRs
typedef __attribute__((ext_vector_type(4))) float f32x4;    // MFMA C/D

__device__ __forceinline__ float b2f(u16 u) {
    union { u32 a; float f; } z;
    z.a = ((u32)u) << 16;
    return z.f;
}

// fp32 -> bf16 with round-to-nearest-even
__device__ __forceinline__ u16 f2b(float v) {
    u32 x = __float_as_uint(v);
    return (u16)((x + 0x7fffu + ((x >> 16) & 1u)) >> 16);
}

// Dtype-flexible input load. isf32: 1 = fp32 tensors, 0 = bf16 tensors.
__device__ __forceinline__ float ldin(const void* p, int idx, int isf32) {
    if (isf32) return ((const float*)p)[idx];
    return b2f(((const u16*)p)[idx]);
}

// async global->LDS, 16 B per lane, dest = wave-uniform base + lane*16
__device__ __forceinline__ void gld_lds16(const void* g, void* l) {
    __builtin_amdgcn_global_load_lds(
        (const __attribute__((address_space(1))) unsigned int*)g,
        (__attribute__((address_space(3))) unsigned int*)l, 16, 0, 0);
}

// Resolve input dtype. hisf >= 0: trusted host answer (from exact in_sizes
// match). Otherwise: wave-level bit-pattern ballot on `content`.
__device__ __forceinline__ int resolve_isf32(int hisf, const void* content) {
    if (hisf >= 0) return hisf;
    int lane = threadIdx.x & 63;
    u16 u = ((const u16*)content)[lane * 2048];
    int e = (u >> 7) & 0xff;
    unsigned long long m = __ballot(e >= 100 && e <= 150);
    return (__popcll(m) < 32) ? 1 : 0;
}

// ===========================================================================
// Role bodies
// ===========================================================================

// Per-wave style stats: one wave owns one (b,c) plane. No barriers, no LDS.
// Butterfly-reduce 5 window terms, build 9 shifted sums in-register, then
// 64 lanes dot with cw1/cw2[o,c,:] and atomicAdd into pooled_raw[set,b,o].
__device__ __forceinline__ void role_style_wave(int bc, const void* style,
        const void* cw1, const void* cw2, float* pooled_raw, int isf32) {
    int b = bc >> 9, c = bc & 511;
    int base = bc * HW;
    int lane = threadIdx.x & 63;
    float t = 0.f, top = 0.f, bot = 0.f, lft = 0.f, rgt = 0.f;
    if (isf32) {
        const float4* sp = (const float4*)((const float*)style + base);
#pragma unroll
        for (int k = 0; k < 16; k++) {
            float4 v = sp[lane + 64 * k];
            float s4 = (v.x + v.y) + (v.z + v.w);
            t += s4;
            if (k == 0  && lane < 16)  top += s4;
            if (k == 15 && lane >= 48) bot += s4;
            if ((lane & 15) == 0)  lft += v.x;
            if ((lane & 15) == 15) rgt += v.w;
        }
    } else {
        const uint4* sp = (const uint4*)((const u16*)style + base);
#pragma unroll
        for (int k = 0; k < 8; k++) {
            uint4 v = sp[lane + 64 * k];
            float e0 = b2f((u16)(v.x & 0xffffu)), e1 = b2f((u16)(v.x >> 16));
            float e2 = b2f((u16)(v.y & 0xffffu)), e3 = b2f((u16)(v.y >> 16));
            float e4 = b2f((u16)(v.z & 0xffffu)), e5 = b2f((u16)(v.z >> 16));
            float e6 = b2f((u16)(v.w & 0xffffu)), e7 = b2f((u16)(v.w >> 16));
            float s8 = ((e0 + e1) + (e2 + e3)) + ((e4 + e5) + (e6 + e7));
            t += s8;
            if (k == 0 && lane < 8)   top += s8;
            if (k == 7 && lane >= 56) bot += s8;
            if ((lane & 7) == 0) lft += e0;
            if ((lane & 7) == 7) rgt += e7;
        }
    }
#pragma unroll
    for (int off = 1; off < 64; off <<= 1) {
        t   += __shfl_xor(t, off);
        top += __shfl_xor(top, off);
        bot += __shfl_xor(bot, off);
        lft += __shfl_xor(lft, off);
        rgt += __shfl_xor(rgt, off);
    }
    float c00 = ldin(style, base + 0,    isf32);
    float c0W = ldin(style, base + 63,   isf32);
    float cH0 = ldin(style, base + 4032, isf32);
    float cHW = ldin(style, base + 4095, isf32);
    float s[9];
    s[0] = t - bot - rgt + cHW;
    s[1] = t - bot;
    s[2] = t - bot - lft + cH0;
    s[3] = t - rgt;
    s[4] = t;
    s[5] = t - lft;
    s[6] = t - top - rgt + c0W;
    s[7] = t - top;
    s[8] = t - top - lft + c00;
    int set = lane >> 5, o = lane & 31;
    const void* cw = set ? cw2 : cw1;
    int wb = (o * NC + c) * 9;
    float acc = 0.f;
#pragma unroll
    for (int k = 0; k < 9; k++) acc += ldin(cw, wb + k, isf32) * s[k];
    atomicAdd(&pooled_raw[(set * NB + b) * 32 + o], acc);
}

// Per-wave transform: content [b][c][h][w] -> cT [(b4*16+ci)][h][w][32] bf16
// with the c-group XOR swizzle baked in (key (w+1)&3). Each wave owns a
// private LDS slice (u16 [32][72]) and loops 4 h-rows; no block barriers.
__device__ __forceinline__ void role_transform_wave(int ridx,
        const void* content, u16* cT, int bstart, int isf32,
        u16* wl /*2304 u16*/) {
    int hq = ridx & 15;
    int ci = (ridx >> 4) & 15;
    int b4 = ridx >> 8;
    int lane = threadIdx.x & 63;
    size_t pbase = ((size_t)(bstart + b4) * NC + ci * 32) * HW;
    int c  = lane >> 1;
    int w0 = (lane & 1) * 32;
    int wq = lane >> 2;             // 0..15: w group for the store phase
    int cq = (lane & 3) * 4;        // cpair base

    for (int i = 0; i < 4; i++) {
        int h = hq * 4 + i;
        // load row chunk -> bf16 -> private LDS [c][w] (stride 72 u16)
        if (isf32) {
            const float* src = (const float*)content + pbase
                               + (size_t)c * HW + h * 64 + w0;
#pragma unroll
            for (int j = 0; j < 8; j++) {
                float4 v = *(const float4*)(src + j * 4);
                u32 lo = (u32)f2b(v.x) | ((u32)f2b(v.y) << 16);
                u32 hi = (u32)f2b(v.z) | ((u32)f2b(v.w) << 16);
                *(uint2*)(wl + c * 72 + w0 + j * 4) = make_uint2(lo, hi);
            }
        } else {
            const u16* src = (const u16*)content + pbase
                             + (size_t)c * HW + h * 64 + w0;
#pragma unroll
            for (int j = 0; j < 4; j++) {
                uint4 v = *(const uint4*)(src + j * 8);
                *(uint4*)(wl + c * 72 + w0 + j * 8) = v;
            }
        }
        asm volatile("s_waitcnt lgkmcnt(0)" ::: "memory");
        // transposed+swizzled read, fully-coalesced dwordx4 stores
        u32* out = (u32*)(cT + (((size_t)(b4 * 16 + ci)) * 4096 + h * 64) * 32);
#pragma unroll
        for (int k = 0; k < 4; k++) {
            int w = wq + 16 * k;
            int key = (w + 1) & 3;
            u32 q[4];
#pragma unroll
            for (int e = 0; e < 4; e++) {
                int p0 = 2 * (cq + e);
                int lc = (((p0 >> 3) ^ key) << 3) | (p0 & 7);
                q[e] = (u32)wl[lc * 72 + w] | ((u32)wl[(lc + 1) * 72 + w] << 16);
            }
            *(uint4*)(out + k * 256 + lane * 4) = make_uint4(q[0], q[1], q[2], q[3]);
        }
        asm volatile("s_waitcnt lgkmcnt(0)" ::: "memory");
    }
}

// Pack ds_w [32][512][3][3] -> MFMA B-fragments (bf16).
__device__ __forceinline__ void role_prep_wdown(int ridx, const void* dsw,
        u16* Bp, int isf32) {
    int idx = ridx * 256 + threadIdx.x;             // < 147456
    int e = idx & 7, l = (idx >> 3) & 63, nf = (idx >> 9) & 1;
    int cb = (idx >> 10) & 15, t9 = idx >> 14;
    int oc = nf * 16 + (l & 15);
    int c = cb * 32 + (l >> 4) * 8 + e;
    Bp[idx] = f2b(ldin(dsw, (oc * NC + c) * 9 + t9, isf32));
}

// Pack up_w [512][32][3][3] -> B2_pack.
__device__ __forceinline__ void role_prep_wup(int ridx, const void* upw,
        u16* B2p, int isf32) {
    int idx = ridx * 256 + threadIdx.x;             // < 147456
    int e = idx & 7, l = (idx >> 3) & 63, nfo = (idx >> 9) & 31, t9 = idx >> 14;
    int oc = nfo * 16 + (l & 15);
    int ic = (l >> 4) * 8 + e;
    B2p[idx] = f2b(ldin(upw, (oc * INNER + ic) * 9 + t9, isf32));
}

// FC (512 threads): f[b,row] = pooled[b,:]·fw[row,:] + fb[row] -> MFMA frags.
// pooled[b,o] = pooled_raw*(1/4096) + conv-bias, applied at read.
__device__ __forceinline__ void role_fc(int ridx, const float* pooled_raw,
        const void* cbf1, const void* cbf2,
        const void* fw1, const void* fb1, const void* fw2, const void* fb2,
        u16* fpack, int isf32, float* p) {
    int set = ridx / 144;
    int rr = ridx - set * 144;
    int b = rr / 18;
    int chunk = rr - b * 18;
    int row = chunk * 512 + threadIdx.x;       // 0..9215
    const void* fw = set ? fw2 : fw1;
    const void* fb = set ? fb2 : fb1;
    if (threadIdx.x < 32)
        p[threadIdx.x] = pooled_raw[(set * NB + b) * 32 + threadIdx.x]
                           * (1.0f / 4096.0f)
                       + ldin(set ? cbf2 : cbf1, threadIdx.x, isf32);
    __syncthreads();
    float acc = ldin(fb, row, isf32);
    if (isf32) {
        const float* fwf = (const float*)fw + row * 32;
#pragma unroll
        for (int j = 0; j < 32; j++) acc += fwf[j] * p[j];
    } else {
        const u32* w32 = (const u32*)((const u16*)fw + row * 32);
#pragma unroll
        for (int j = 0; j < 16; j++) {
            u32 u = w32[j];
            acc += b2f((u16)(u & 0xffffu)) * p[2 * j];
            acc += b2f((u16)(u >> 16)) * p[2 * j + 1];
        }
    }
    int oc = row / 288;
    int rem = row - oc * 288;
    int ic = rem / 9;
    int t9 = rem - ic * 9;
    int l = (oc & 15) | ((ic >> 3) << 4);
    int e = ic & 7;
    int nf = oc >> 4;
    fpack[((((set * NB + b) * 9 + t9) * 2 + nf) * 64 + l) * 8 + e] = f2b(acc);
}

// Conv 512->32 MFMA implicit GEMM (512 threads, 8 waves: 4 px-quarters x
// 2 oc-frags). Reads pre-transposed+swizzled cT.
__device__ __forceinline__ void role_conv_down(int x, const u16* cT,
        const u16* Bp, const void* dsb, u16* c0T, int bstart, int isf32,
        u16* lds) {
    u32* lds32 = (u32*)lds;
    int b4 = x >> 6, row = x & 63;
    int b = bstart + b4;
    int tid = threadIdx.x, lane = tid & 63;
    int wid = __builtin_amdgcn_readfirstlane(tid >> 6);   // 0..7
    // zero everything once: halo cols + out-of-range rows stay zero forever
    for (int i = tid; i < 3 * 66 * 16; i += 512) lds32[i] = 0u;
    __syncthreads();

    int m = lane & 15, g = lane >> 4;
    int wq = wid & 3, ocf = wid >> 2;
    int wbase = wq * 16;
    int sr = wid >> 1, sh = wid & 1;        // staging row/half (wid < 6)
    f32x4 acc = {0.f, 0.f, 0.f, 0.f};

    for (int ci = 0; ci < 16; ci++) {
        if (ci) __syncthreads();
        const u16* sp = cT + ((size_t)(b4 * 16 + ci) * 4096) * 32;
        if (wid < 6) {
            int gh = row + sr - 1;
            if (gh >= 0 && gh < 64)
                gld_lds16(sp + (size_t)gh * 2048 + (sh * 64 + lane) * 8,
                          (char*)lds + (sr * 66 + 1) * 64 + sh * 1024);
        }
        __syncthreads();
#pragma unroll
        for (int t9 = 0; t9 < 9; t9++) {
            int dh = t9 / 3, dw = t9 - dh * 3;
            int wi = wbase + m + dw;
            bf16x8 a = *(const bf16x8*)(lds + ((dh * 66 + wi) * 32 + ((g ^ (wi & 3)) * 8)));
            bf16x8 bb = ((const bf16x8*)Bp)[((t9 * 16 + ci) * 2 + ocf) * 64 + lane];
            acc = __builtin_amdgcn_mfma_f32_16x16x32_bf16(a, bb, acc, 0, 0, 0);
        }
    }
    int oc = ocf * 16 + m;
    float bia = ldin(dsb, oc, isf32);
    size_t obase = ((size_t)b * 4096 + row * 64) * 32;
    int pix0 = wbase + g * 4;
#pragma unroll
    for (int r = 0; r < 4; r++) {
        int w = pix0 + r;
        int key = (w + 1) & 3;
        int p = (((oc >> 3) ^ key) << 3) | (oc & 7);
        c0T[obase + (size_t)w * 32 + p] = f2b(acc[r] + bia);
    }
}

// ===========================================================================
// Merged launches
// ===========================================================================

// Front (256 thr): style(per-wave) | transform(per-wave) | prep_wdown | prep_wup
__global__ __launch_bounds__(256) void k_front(
        const void* __restrict__ style,
        const void* __restrict__ cw1, const void* __restrict__ cw2,
        float* __restrict__ pooled_raw, int nStyleB,
        const void* __restrict__ content, u16* __restrict__ cT, int bstart, int nTB,
        const void* __restrict__ dsw, u16* __restrict__ Bp,
        const void* __restrict__ upw, u16* __restrict__ B2p, int nPrep,
        int hisf) {
    __shared__ u16 smT[4][2304];        // per-wave transform slices
    int isf32 = resolve_isf32(hisf, content);
    int wid = threadIdx.x >> 6;
    int x = blockIdx.x;
    if (x < nStyleB) {
        role_style_wave(x * 4 + wid, style, cw1, cw2, pooled_raw, isf32);
        return;
    }
    x -= nStyleB;
    if (x < nTB) {
        role_transform_wave(x * 4 + wid, content, cT, bstart, isf32, smT[wid]);
        return;
    }
    x -= nTB;
    if (x < nPrep) { role_prep_wdown(x, dsw, Bp, isf32); return; }
    x -= nPrep;
    role_prep_wup(x, upw, B2p, isf32);
}

// Mid (512 thr): conv_down | fc
__global__ __launch_bounds__(512) void k_mid(
        const u16* __restrict__ cT, const u16* __restrict__ Bp,
        const void* __restrict__ dsb, u16* __restrict__ c0T, int bstart, int nCD,
        const float* __restrict__ pooled_raw,
        const void* __restrict__ cbf1, const void* __restrict__ cbf2,
        const void* __restrict__ fw1, const void* __restrict__ fb1,
        const void* __restrict__ fw2, const void* __restrict__ fb2,
        u16* __restrict__ fpack, const void* __restrict__ content, int hisf) {
    __shared__ u16 lds[3 * 66 * 32];
    int isf32 = resolve_isf32(hisf, content);
    int x = blockIdx.x;
    if (x < nCD) { role_conv_down(x, cT, Bp, dsb, c0T, bstart, isf32, lds); return; }
    role_fc(x - nCD, pooled_raw, cbf1, cbf2, fw1, fb1, fw2, fb2, fpack,
            isf32, (float*)lds);
}

// ---------------------------------------------------------------------------
// Per-sample dynamic 32->32 conv (MFMA, 512 thr: 4 px-quarters x 2 oc-frags)
// + optional LeakyReLU. srcT/dstT: [b][h][w][32] bf16, swizzled.
// ---------------------------------------------------------------------------
__global__ __launch_bounds__(512) void k_apply(const u16* __restrict__ srcT,
        const u16* __restrict__ fpack, u16* __restrict__ dstT, int lrelu) {
    int b = blockIdx.x >> 6, row = blockIdx.x & 63;
    int tid = threadIdx.x, lane = tid & 63;
    int wid = __builtin_amdgcn_readfirstlane(tid >> 6);   // 0..7
    __shared__ u16 lds[3 * 66 * 32];
    u32* lds32 = (u32*)lds;
    for (int i = tid; i < 96; i += 512) {
        int r = i >> 5, side = (i >> 4) & 1, cpr = i & 15;
        lds32[(r * 66 + side * 65) * 16 + cpr] = 0u;
    }
    const u16* sp = srcT + (size_t)b * 64 * 64 * 32;
    if (wid < 6) {
        int sr = wid >> 1, sh = wid & 1;
        int gh = row + sr - 1;
        u32 ldsoff = (u32)(sr * 66 + 1) * 64 + (u32)sh * 1024;
        if (gh >= 0 && gh < 64) {
            gld_lds16(sp + (size_t)gh * 2048 + (sh * 64 + lane) * 8,
                      (char*)lds + ldsoff);
        } else {
            int4 z = make_int4(0, 0, 0, 0);
            *(int4*)((char*)lds + ldsoff + (u32)lane * 16) = z;
        }
    }
    __syncthreads();

    int m = lane & 15, g = lane >> 4;
    int wq = wid & 3, ocf = wid >> 2;
    int wbase = wq * 16;
    f32x4 acc = {0.f, 0.f, 0.f, 0.f};
    const bf16x8* FB = (const bf16x8*)fpack + (size_t)b * 1152;
#pragma unroll
    for (int t9 = 0; t9 < 9; t9++) {
        int dh = t9 / 3, dw = t9 - dh * 3;
        int wi = wbase + m + dw;
        bf16x8 a = *(const bf16x8*)(lds + ((dh * 66 + wi) * 32 + ((g ^ (wi & 3)) * 8)));
        bf16x8 bb = FB[(t9 * 2 + ocf) * 64 + lane];
        acc = __builtin_amdgcn_mfma_f32_16x16x32_bf16(a, bb, acc, 0, 0, 0);
    }
    int oc = ocf * 16 + m;
    size_t obase = ((size_t)(b * 64 + row) * 64) * 32;
    int pix0 = wbase + g * 4;
#pragma unroll
    for (int r = 0; r < 4; r++) {
        float v = acc[r];
        if (lrelu) v = (v >= 0.f) ? v : 0.2f * v;
        int w = pix0 + r;
        int key = (w + 1) & 3;
        int p = (((oc >> 3) ^ key) << 3) | (oc & 7);
        dstT[obase + (size_t)w * 32 + p] = f2b(v);
    }
}

// ---------------------------------------------------------------------------
// Conv 32->512 (MFMA) + bias + residual -> out. blockIdx.y = oc quarter.
// Epilogue bounced through LDS [oc][px] (stride 68, 2 halves of 64 oc) so
// the residual loads and output stores are 16-lane-contiguous (256 B).
// ---------------------------------------------------------------------------
__global__ __launch_bounds__(256) void k_conv_up(const u16* __restrict__ c2T,
        const u16* __restrict__ B2p, const void* __restrict__ upb,
        const void* __restrict__ content, void* __restrict__ outv, int hisf) {
    int isf32 = resolve_isf32(hisf, content);
    int b = blockIdx.x >> 6, row = blockIdx.x & 63;
    int nq = blockIdx.y;                           // 0..3
    int tid = threadIdx.x, lane = tid & 63;
    int wid = __builtin_amdgcn_readfirstlane(tid >> 6);
    __shared__ char smem[64 * 68 * 4] __attribute__((aligned(16)));  // 17408 B
    u16* lds = (u16*)smem;
    u32* lds32 = (u32*)smem;
    for (int i = tid; i < 96; i += 256) {
        int r = i >> 5, side = (i >> 4) & 1, cpr = i & 15;
        lds32[(r * 66 + side * 65) * 16 + cpr] = 0u;
    }
    const u16* sp = c2T + (size_t)b * 64 * 64 * 32;
    for (int r = 0; r < 3; r++) {
        int gh = row + r - 1;
        u32 ldsoff = (u32)(r * 66 + 1) * 64 + (u32)wid * 1024;
        if (gh >= 0 && gh < 64) {
            gld_lds16(sp + (size_t)gh * 2048 + tid * 8, (char*)lds + ldsoff);
        } else {
            int4 z = make_int4(0, 0, 0, 0);
            *(int4*)((char*)lds + ldsoff + (u32)lane * 16) = z;
        }
    }
    __syncthreads();

    int m = lane & 15, g = lane >> 4, wbase = wid * 16;
    f32x4 acc[8];
#pragma unroll
    for (int i = 0; i < 8; i++) acc[i] = (f32x4){0.f, 0.f, 0.f, 0.f};
#pragma unroll
    for (int t9 = 0; t9 < 9; t9++) {
        int dh = t9 / 3, dw = t9 - dh * 3;
        int wi = wbase + m + dw;
        bf16x8 a = *(const bf16x8*)(lds + ((dh * 66 + wi) * 32 + ((g ^ (wi & 3)) * 8)));
#pragma unroll
        for (int nfl = 0; nfl < 8; nfl++) {
            bf16x8 bw = ((const bf16x8*)B2p)[(t9 * 32 + nq * 8 + nfl) * 64 + lane];
            acc[nfl] = __builtin_amdgcn_mfma_f32_16x16x32_bf16(a, bw, acc[nfl], 0, 0, 0);
        }
    }

    // Coalesced epilogue via LDS: two halves of 64 oc, [ocl][px] stride 68.
    int pix0 = wbase + g * 4;
    float* fl = (float*)smem;
    int ocl2 = tid >> 4;            // 0..15
    int px0 = (tid & 15) * 4;       // 0..60
    __syncthreads();                // input tile dead
#pragma unroll
    for (int hf = 0; hf < 2; hf++) {
        if (hf) __syncthreads();
#pragma unroll
        for (int nf = 0; nf < 4; nf++) {
            int ocl = nf * 16 + m;
            *(f32x4*)(fl + ocl * 68 + pix0) = acc[hf * 4 + nf];
        }
        __syncthreads();
#pragma unroll
        for (int p = 0; p < 4; p++) {
            int ocl = p * 16 + ocl2;
            int oc = nq * 128 + hf * 64 + ocl;
            float bias = ldin(upb, oc, isf32);
            f32x4 v4 = *(const f32x4*)(fl + ocl * 68 + px0);
            size_t idx = ((size_t)b * NC + oc) * HW + (size_t)row * 64 + px0;
            if (isf32) {
                f32x4 rsd = *(const f32x4*)((const float*)content + idx);
                f32x4 ov;
#pragma unroll
                for (int r = 0; r < 4; r++) ov[r] = v4[r] + bias + rsd[r];
                *(f32x4*)((float*)outv + idx) = ov;
            } else {
                ushort4 rv = *(const ushort4*)((const u16*)content + idx);
                ushort4 ov;
                ov.x = f2b(v4[0] + bias + b2f(rv.x));
                ov.y = f2b(v4[1] + bias + b2f(rv.y));
                ov.z = f2b(v4[2] + bias + b2f(rv.z));
                ov.w = f2b(v4[3] + bias + b2f(rv.w));
                *(ushort4*)((u16*)outv + idx) = ov;
            }
        }
    }
}

// ---------------------------------------------------------------------------
extern "C" void kernel_launch(void* const* d_in, const int* in_sizes, int n_in,
                              void* d_out, int out_size, void* d_ws, size_t ws_size,
                              hipStream_t stream) {
    const void* content = d_in[0];
    const void* style   = d_in[1];
    const void* ds_w    = d_in[2];
    const void* ds_b    = d_in[3];
    const void* up_w    = d_in[4];
    const void* up_b    = d_in[5];
    const void* f1_cw   = d_in[6];
    const void* f1_cb   = d_in[7];
    const void* f1_fw   = d_in[8];
    const void* f1_fb   = d_in[9];
    const void* f2_cw   = d_in[10];
    const void* f2_cb   = d_in[11];
    const void* f2_fw   = d_in[12];
    const void* f2_fb   = d_in[13];

    // Host-side dtype resolution from exact input byte sizes; -1 = unknown,
    // kernels fall back to wave-ballot bit detection.
    int hisf = -1;
    if (in_sizes && n_in >= 1) {
        if (in_sizes[0] == NB * NC * HW * 4) hisf = 1;
        else if (in_sizes[0] == NB * NC * HW * 2) hisf = 0;
    }

    const size_t SZ_PACK = 294912;       // 147456 u16
    const size_t SZ_CT2  = 2097152;      // 1,048,576 u16 (32-ch bf16 tensor)
    const size_t REQ_WS  = 3 * SZ_CT2 + 3 * SZ_PACK + 2048 + 64;

    if (ws_size >= REQ_WS) {
        // FULL path: all intermediates in d_ws; d_out holds only cT (full
        // batch, 33,554,432 B <= out_size), dead before k_conv_up writes out.
        char* w = (char*)d_ws;
        u16*   B2pack = (u16*)w;                 w += SZ_PACK;
        u16*   c2T    = (u16*)w;                 w += SZ_CT2;
        u16*   c0T    = (u16*)w;                 w += SZ_CT2;
        u16*   c1T    = (u16*)w;                 w += SZ_CT2;
        u16*   Bpack  = (u16*)w;                 w += SZ_PACK;
        u16*   fpack  = (u16*)w;                 w += SZ_PACK;
        float* pooled_raw = (float*)w;
        u16*   cT     = (u16*)d_out;

        hipMemsetAsync(pooled_raw, 0, 2 * NB * 32 * 4, stream);
        // L1: style(1024 blk, 1 plane/wave) + transform(512 blk, 4 rows/wave)
        //     + preps(2x576)
        k_front<<<1024 + 512 + 2 * 576, 256, 0, stream>>>(
            style, f1_cw, f2_cw, pooled_raw, 1024,
            content, cT, 0, 512,
            ds_w, Bpack, up_w, B2pack, 576, hisf);
        // L2: conv_down(512, 8-wave) + fc(288, 512-thr)
        k_mid<<<512 + 288, 512, 0, stream>>>(
            cT, Bpack, ds_b, c0T, 0, 512,
            pooled_raw, f1_cb, f2_cb,
            f1_fw, f1_fb, f2_fw, f2_fb, fpack, content, hisf);
        // L3/L4: dynamic convs (8-wave)
        k_apply<<<NB * 64, 512, 0, stream>>>(c0T, fpack, c1T, 1);
        k_apply<<<NB * 64, 512, 0, stream>>>(c1T, fpack + NB * 9216, c2T, 0);
        // L5: conv_up
        k_conv_up<<<dim3(NB * 64, 4), 256, 0, stream>>>(c2T, B2pack, up_b,
                                                        content, d_out, hisf);
    } else {
        // HALF path (small ws): scratch in d_out, cT half-batch reused.
        float* pooled_raw = (float*)d_out;           //       512 f32
        u16*   fpack  = (u16*)(pooled_raw + 512);    //   147,456 u16
        u16*   Bpack  = fpack + 147456;              //   147,456 u16
        u16*   c0T    = Bpack + 147456;              // 1,048,576 u16
        u16*   c1T    = c0T + 1048576;               // 1,048,576 u16
        u16*   cTh    = c1T + 1048576;               // 8,388,608 u16
        u16*   B2pack = (u16*)d_ws;                  //   147,456 u16
        u16*   c2T    = B2pack + 147456;             // 1,048,576 u16

        hipMemsetAsync(pooled_raw, 0, 2 * NB * 32 * 4, stream);
        // L1: style + transform(half0, 256 blk) + preps
        k_front<<<1024 + 256 + 2 * 576, 256, 0, stream>>>(
            style, f1_cw, f2_cw, pooled_raw, 1024,
            content, cTh, 0, 256,
            ds_w, Bpack, up_w, B2pack, 576, hisf);
        // L2: conv_down(half0) + fc
        k_mid<<<256 + 288, 512, 0, stream>>>(
            cTh, Bpack, ds_b, c0T, 0, 256,
            pooled_raw, f1_cb, f2_cb,
            f1_fw, f1_fb, f2_fw, f2_fb, fpack, content, hisf);
        // L3: transform(half1)
        k_front<<<256, 256, 0, stream>>>(
            style, f1_cw, f2_cw, pooled_raw, 0,
            content, cTh, 4, 256,
            ds_w, Bpack, up_w, B2pack, 0, hisf);
        // L4: conv_down(half1)
        k_mid<<<256, 512, 0, stream>>>(
            cTh, Bpack, ds_b, c0T, 4, 256,
            pooled_raw, f1_cb, f2_cb,
            f1_fw, f1_fb, f2_fw, f2_fb, fpack, content, hisf);
        // L5/L6: dynamic convs
        k_apply<<<NB * 64, 512, 0, stream>>>(c0T, fpack, c1T, 1);
        k_apply<<<NB * 64, 512, 0, stream>>>(c1T, fpack + NB * 9216, c2T, 0);
        // L7: conv_up
        k_conv_up<<<dim3(NB * 64, 4), 256, 0, stream>>>(c2T, B2pack, up_b,
                                                        content, d_out, hisf);
    }
}

// Round 7
// 280.862 us; speedup vs baseline: 1.0101x; 1.0053x over previous
//
#include <hip/hip_runtime.h>
#include <hip/hip_bf16.h>

// Problem constants
#define NB 8
#define NC 512
#define HW 4096
#define INNER 32

typedef unsigned short u16;
typedef unsigned int u32;
typedef __attribute__((ext_vector_type(8))) short bf16x8;   // 8 bf16 = 4 VGPRs
typedef __attribute__((ext_vector_type(4))) float f32x4;    // MFMA C/D

__device__ __forceinline__ float b2f(u16 u) {
    union { u32 a; float f; } z;
    z.a = ((u32)u) << 16;
    return z.f;
}

// fp32 -> bf16 with round-to-nearest-even
__device__ __forceinline__ u16 f2b(float v) {
    u32 x = __float_as_uint(v);
    return (u16)((x + 0x7fffu + ((x >> 16) & 1u)) >> 16);
}

// Dtype-flexible input load. isf32: 1 = fp32 tensors, 0 = bf16 tensors.
__device__ __forceinline__ float ldin(const void* p, int idx, int isf32) {
    if (isf32) return ((const float*)p)[idx];
    return b2f(((const u16*)p)[idx]);
}

// async global->LDS, 16 B per lane, dest = wave-uniform base + lane*16
__device__ __forceinline__ void gld_lds16(const void* g, void* l) {
    __builtin_amdgcn_global_load_lds(
        (const __attribute__((address_space(1))) unsigned int*)g,
        (__attribute__((address_space(3))) unsigned int*)l, 16, 0, 0);
}

// Resolve input dtype. hisf >= 0: trusted host answer (from exact in_sizes
// match). Otherwise: wave-level bit-pattern ballot on `content`.
__device__ __forceinline__ int resolve_isf32(int hisf, const void* content) {
    if (hisf >= 0) return hisf;
    int lane = threadIdx.x & 63;
    u16 u = ((const u16*)content)[lane * 2048];
    int e = (u >> 7) & 0xff;
    unsigned long long m = __ballot(e >= 100 && e <= 150);
    return (__popcll(m) < 32) ? 1 : 0;
}

// ===========================================================================
// Role bodies (R5-proven forms)
// ===========================================================================

// Style stats per (b,c) plane (vectorized) + fused pooled contribution.
__device__ __forceinline__ void role_style(int bc, const void* style,
        const void* cw1, const void* cw2, float* pooled_raw,
        int isf32, float* smf) {
    int b = bc >> 9, c = bc & 511;
    int base = bc * HW;
    int tid = threadIdx.x;
    float t = 0.f, top = 0.f, bot = 0.f, lft = 0.f, rgt = 0.f;
    if (isf32) {
        const float4* sp = (const float4*)((const float*)style + base);
#pragma unroll
        for (int k = 0; k < 4; k++) {
            int q = tid + k * 256;              // float4 idx 0..1023
            float4 v = sp[q];
            float s4 = (v.x + v.y) + (v.z + v.w);
            int h = q >> 4, w0 = (q & 15) * 4;
            t += s4;
            if (h == 0)   top += s4;
            if (h == 63)  bot += s4;
            if (w0 == 0)  lft += v.x;
            if (w0 == 60) rgt += v.w;
        }
    } else {
        const uint4* sp = (const uint4*)((const u16*)style + base);
#pragma unroll
        for (int k = 0; k < 2; k++) {
            int q = tid + k * 256;              // 8-elem idx 0..511
            uint4 v = sp[q];
            float e0 = b2f((u16)(v.x & 0xffffu)), e1 = b2f((u16)(v.x >> 16));
            float e2 = b2f((u16)(v.y & 0xffffu)), e3 = b2f((u16)(v.y >> 16));
            float e4 = b2f((u16)(v.z & 0xffffu)), e5 = b2f((u16)(v.z >> 16));
            float e6 = b2f((u16)(v.w & 0xffffu)), e7 = b2f((u16)(v.w >> 16));
            float s8 = ((e0 + e1) + (e2 + e3)) + ((e4 + e5) + (e6 + e7));
            int h = q >> 3, w0 = (q & 7) * 8;
            t += s8;
            if (h == 0)   top += s8;
            if (h == 63)  bot += s8;
            if (w0 == 0)  lft += e0;
            if (w0 == 56) rgt += e7;
        }
    }
#pragma unroll
    for (int off = 32; off > 0; off >>= 1) {
        t   += __shfl_down(t, off);
        top += __shfl_down(top, off);
        bot += __shfl_down(bot, off);
        lft += __shfl_down(lft, off);
        rgt += __shfl_down(rgt, off);
    }
    int wave = tid >> 6;
    if ((tid & 63) == 0) {
        smf[20 + wave * 5 + 0] = t;   smf[20 + wave * 5 + 1] = top;
        smf[20 + wave * 5 + 2] = bot; smf[20 + wave * 5 + 3] = lft;
        smf[20 + wave * 5 + 4] = rgt;
    }
    __syncthreads();
    if (tid == 0) {
        t   = smf[20] + smf[25] + smf[30] + smf[35];
        top = smf[21] + smf[26] + smf[31] + smf[36];
        bot = smf[22] + smf[27] + smf[32] + smf[37];
        lft = smf[23] + smf[28] + smf[33] + smf[38];
        rgt = smf[24] + smf[29] + smf[34] + smf[39];
        float c00 = ldin(style, base + 0,    isf32);
        float c0W = ldin(style, base + 63,   isf32);
        float cH0 = ldin(style, base + 4032, isf32);
        float cHW = ldin(style, base + 4095, isf32);
        smf[0] = t - bot - rgt + cHW;
        smf[1] = t - bot;
        smf[2] = t - bot - lft + cH0;
        smf[3] = t - rgt;
        smf[4] = t;
        smf[5] = t - lft;
        smf[6] = t - top - rgt + c0W;
        smf[7] = t - top;
        smf[8] = t - top - lft + c00;
    }
    __syncthreads();
    if (tid < 64) {
        int set = tid >> 5, o = tid & 31;
        const void* cw = set ? cw2 : cw1;
        int wb = (o * NC + c) * 9;
        float acc = 0.f;
#pragma unroll
        for (int k = 0; k < 9; k++) acc += ldin(cw, wb + k, isf32) * smf[k];
        atomicAdd(&pooled_raw[(set * NB + b) * 32 + o], acc);
    }
}

// Transpose content [b][c][h][w] -> cT [(b4*16+ci)][h][w][32] bf16 with the
// c-group XOR swizzle baked in (key (w+1)&3). 2 h-rows per block.
__device__ __forceinline__ void role_transform(int ridx, const void* content,
        u16* cT, int bstart, int isf32, float* lds) {
    int hp = ridx & 31;                 // h-pair: rows 2hp, 2hp+1
    int ci = (ridx >> 5) & 15;
    int b4 = ridx >> 9;
    int tid = threadIdx.x;
    size_t gbase = ((size_t)(bstart + b4) * NC + ci * 32) * HW + (size_t)hp * 128;
    if (isf32) {
#pragma unroll
        for (int r2 = 0; r2 < 2; r2++)
#pragma unroll
            for (int k = 0; k < 2; k++) {
                int q = tid + k * 256;                  // 0..511 float4s
                int c = q >> 4, w0 = (q & 15) * 4;
                float4 v = *(const float4*)((const float*)content
                            + gbase + (size_t)c * HW + r2 * 64 + w0);
                float* dst = lds + r2 * 2080 + c * 65 + w0;
                dst[0] = v.x; dst[1] = v.y; dst[2] = v.z; dst[3] = v.w;
            }
    } else {
#pragma unroll
        for (int r2 = 0; r2 < 2; r2++) {
            int c = tid >> 3, w0 = (tid & 7) * 8;
            uint4 v = *(const uint4*)((const u16*)content
                        + gbase + (size_t)c * HW + r2 * 64 + w0);
            float* dst = lds + r2 * 2080 + c * 65 + w0;
            dst[0] = b2f((u16)(v.x & 0xffffu));
            dst[1] = b2f((u16)(v.x >> 16));
            dst[2] = b2f((u16)(v.y & 0xffffu));
            dst[3] = b2f((u16)(v.y >> 16));
            dst[4] = b2f((u16)(v.z & 0xffffu));
            dst[5] = b2f((u16)(v.z >> 16));
            dst[6] = b2f((u16)(v.w & 0xffffu));
            dst[7] = b2f((u16)(v.w >> 16));
        }
    }
    __syncthreads();
#pragma unroll
    for (int r2 = 0; r2 < 2; r2++) {
        u32* out = (u32*)(cT + ((size_t)(b4 * 16 + ci) * 4096
                                + (hp * 2 + r2) * 64) * 32);
        const float* src = lds + r2 * 2080;
#pragma unroll
        for (int k = 0; k < 4; k++) {
            int j = tid + k * 256;          // 0..1023 u32 slots
            int w = j >> 4, cpair = j & 15;
            int key = (w + 1) & 3;
            int p0 = cpair << 1;
            int lc = (((p0 >> 3) ^ key) << 3) | (p0 & 7);
            out[j] = (u32)f2b(src[lc * 65 + w])
                   | ((u32)f2b(src[(lc + 1) * 65 + w]) << 16);
        }
    }
}

// Pack ds_w [32][512][3][3] -> MFMA B-fragments (bf16).
__device__ __forceinline__ void role_prep_wdown(int ridx, const void* dsw,
        u16* Bp, int isf32) {
    int idx = ridx * 256 + threadIdx.x;             // < 147456
    int e = idx & 7, l = (idx >> 3) & 63, nf = (idx >> 9) & 1;
    int cb = (idx >> 10) & 15, t9 = idx >> 14;
    int oc = nf * 16 + (l & 15);
    int c = cb * 32 + (l >> 4) * 8 + e;
    Bp[idx] = f2b(ldin(dsw, (oc * NC + c) * 9 + t9, isf32));
}

// Pack up_w [512][32][3][3] -> B2_pack.
__device__ __forceinline__ void role_prep_wup(int ridx, const void* upw,
        u16* B2p, int isf32) {
    int idx = ridx * 256 + threadIdx.x;             // < 147456
    int e = idx & 7, l = (idx >> 3) & 63, nfo = (idx >> 9) & 31, t9 = idx >> 14;
    int oc = nfo * 16 + (l & 15);
    int ic = (l >> 4) * 8 + e;
    B2p[idx] = f2b(ldin(upw, (oc * INNER + ic) * 9 + t9, isf32));
}

// FC (512 threads): f[b,row] = pooled[b,:]·fw[row,:] + fb[row] -> MFMA frags.
__device__ __forceinline__ void role_fc(int ridx, const float* pooled_raw,
        const void* cbf1, const void* cbf2,
        const void* fw1, const void* fb1, const void* fw2, const void* fb2,
        u16* fpack, int isf32, float* p) {
    int set = ridx / 144;
    int rr = ridx - set * 144;
    int b = rr / 18;
    int chunk = rr - b * 18;
    int row = chunk * 512 + threadIdx.x;       // 0..9215
    const void* fw = set ? fw2 : fw1;
    const void* fb = set ? fb2 : fb1;
    if (threadIdx.x < 32)
        p[threadIdx.x] = pooled_raw[(set * NB + b) * 32 + threadIdx.x]
                           * (1.0f / 4096.0f)
                       + ldin(set ? cbf2 : cbf1, threadIdx.x, isf32);
    __syncthreads();
    float acc = ldin(fb, row, isf32);
    if (isf32) {
        const float* fwf = (const float*)fw + row * 32;
#pragma unroll
        for (int j = 0; j < 32; j++) acc += fwf[j] * p[j];
    } else {
        const u32* w32 = (const u32*)((const u16*)fw + row * 32);
#pragma unroll
        for (int j = 0; j < 16; j++) {
            u32 u = w32[j];
            acc += b2f((u16)(u & 0xffffu)) * p[2 * j];
            acc += b2f((u16)(u >> 16)) * p[2 * j + 1];
        }
    }
    int oc = row / 288;
    int rem = row - oc * 288;
    int ic = rem / 9;
    int t9 = rem - ic * 9;
    int l = (oc & 15) | ((ic >> 3) << 4);
    int e = ic & 7;
    int nf = oc >> 4;
    fpack[((((set * NB + b) * 9 + t9) * 2 + nf) * 64 + l) * 8 + e] = f2b(acc);
}

// Conv 512->32 MFMA implicit GEMM (512 threads, 8 waves).
__device__ __forceinline__ void role_conv_down(int x, const u16* cT,
        const u16* Bp, const void* dsb, u16* c0T, int bstart, int isf32,
        u16* lds) {
    u32* lds32 = (u32*)lds;
    int b4 = x >> 6, row = x & 63;
    int b = bstart + b4;
    int tid = threadIdx.x, lane = tid & 63;
    int wid = __builtin_amdgcn_readfirstlane(tid >> 6);   // 0..7
    for (int i = tid; i < 3 * 66 * 16; i += 512) lds32[i] = 0u;
    __syncthreads();

    int m = lane & 15, g = lane >> 4;
    int wq = wid & 3, ocf = wid >> 2;
    int wbase = wq * 16;
    int sr = wid >> 1, sh = wid & 1;        // staging row/half (wid < 6)
    f32x4 acc = {0.f, 0.f, 0.f, 0.f};

    for (int ci = 0; ci < 16; ci++) {
        if (ci) __syncthreads();
        const u16* sp = cT + ((size_t)(b4 * 16 + ci) * 4096) * 32;
        if (wid < 6) {
            int gh = row + sr - 1;
            if (gh >= 0 && gh < 64)
                gld_lds16(sp + (size_t)gh * 2048 + (sh * 64 + lane) * 8,
                          (char*)lds + (sr * 66 + 1) * 64 + sh * 1024);
        }
        __syncthreads();
#pragma unroll
        for (int t9 = 0; t9 < 9; t9++) {
            int dh = t9 / 3, dw = t9 - dh * 3;
            int wi = wbase + m + dw;
            bf16x8 a = *(const bf16x8*)(lds + ((dh * 66 + wi) * 32 + ((g ^ (wi & 3)) * 8)));
            bf16x8 bb = ((const bf16x8*)Bp)[((t9 * 16 + ci) * 2 + ocf) * 64 + lane];
            acc = __builtin_amdgcn_mfma_f32_16x16x32_bf16(a, bb, acc, 0, 0, 0);
        }
    }
    int oc = ocf * 16 + m;
    float bia = ldin(dsb, oc, isf32);
    size_t obase = ((size_t)b * 4096 + row * 64) * 32;
    int pix0 = wbase + g * 4;
#pragma unroll
    for (int r = 0; r < 4; r++) {
        int w = pix0 + r;
        int key = (w + 1) & 3;
        int p = (((oc >> 3) ^ key) << 3) | (oc & 7);
        c0T[obase + (size_t)w * 32 + p] = f2b(acc[r] + bia);
    }
}

// ===========================================================================
// Merged launches
// ===========================================================================

// Front (256 thr): style(+pooled) | transform | prep_wdown | prep_wup
__global__ __launch_bounds__(256) void k_front(
        const void* __restrict__ style,
        const void* __restrict__ cw1, const void* __restrict__ cw2,
        float* __restrict__ pooled_raw, int nStyle,
        const void* __restrict__ content, u16* __restrict__ cT, int bstart, int nT,
        const void* __restrict__ dsw, u16* __restrict__ Bp,
        const void* __restrict__ upw, u16* __restrict__ B2p, int nPrep,
        int hisf) {
    __shared__ float smf[2 * 2080];     // transform: 2 rows; style: 40 floats
    int isf32 = resolve_isf32(hisf, content);
    int x = blockIdx.x;
    if (x < nStyle) { role_style(x, style, cw1, cw2, pooled_raw, isf32, smf); return; }
    x -= nStyle;
    if (x < nT) { role_transform(x, content, cT, bstart, isf32, smf); return; }
    x -= nT;
    if (x < nPrep) { role_prep_wdown(x, dsw, Bp, isf32); return; }
    x -= nPrep;
    role_prep_wup(x, upw, B2p, isf32);
}

// Mid (512 thr): conv_down | fc
__global__ __launch_bounds__(512) void k_mid(
        const u16* __restrict__ cT, const u16* __restrict__ Bp,
        const void* __restrict__ dsb, u16* __restrict__ c0T, int bstart, int nCD,
        const float* __restrict__ pooled_raw,
        const void* __restrict__ cbf1, const void* __restrict__ cbf2,
        const void* __restrict__ fw1, const void* __restrict__ fb1,
        const void* __restrict__ fw2, const void* __restrict__ fb2,
        u16* __restrict__ fpack, const void* __restrict__ content, int hisf) {
    __shared__ u16 lds[3 * 66 * 32];
    int isf32 = resolve_isf32(hisf, content);
    int x = blockIdx.x;
    if (x < nCD) { role_conv_down(x, cT, Bp, dsb, c0T, bstart, isf32, lds); return; }
    role_fc(x - nCD, pooled_raw, cbf1, cbf2, fw1, fb1, fw2, fb2, fpack,
            isf32, (float*)lds);
}

// ---------------------------------------------------------------------------
// Fused dynamic convs: c0 -> (filt1, lrelu) -> c1 (LDS only) -> (filt2) -> c2.
// Block = (b,row), 512 thr / 8 waves. Stages 5 c0 rows, computes 3 c1 rows
// into LDS (zero-padded halo), then the c2 row. Removes the c1 global
// round-trip and one launch.
// ---------------------------------------------------------------------------
__global__ __launch_bounds__(512) void k_apply2(const u16* __restrict__ c0T,
        const u16* __restrict__ fpack, u16* __restrict__ c2T) {
    int b = blockIdx.x >> 6, row = blockIdx.x & 63;
    int tid = threadIdx.x, lane = tid & 63;
    int wid = __builtin_amdgcn_readfirstlane(tid >> 6);   // 0..7
    __shared__ u16 A[5 * 66 * 32];     // c0 rows row-2..row+2 (swizzled layout)
    __shared__ u16 B[3 * 66 * 32];     // c1 rows row-1..row+1
    u32* A32 = (u32*)A;
    u32* B32 = (u32*)B;
    // zero A halo columns (wi=0,65); zero all of B (covers halo + invalid rows)
    for (int i = tid; i < 160; i += 512) {
        int r = i / 32, side = (i >> 4) & 1, cpr = i & 15;
        A32[(r * 66 + side * 65) * 16 + cpr] = 0u;
    }
    for (int i = tid; i < 3 * 66 * 16; i += 512) B32[i] = 0u;
    // stage c0 rows row-2..row+2 (20 x 1KB wave-calls over 8 waves)
    const u16* sp = c0T + (size_t)b * 4096 * 32;
#pragma unroll
    for (int i = 0; i < 3; i++) {
        int t = wid + i * 8;
        if (t < 20) {
            int r = t >> 2, seg = t & 3;
            int gh = row + r - 2;
            char* dst = (char*)A + r * 4224 + 64 + seg * 1024;
            if (gh >= 0 && gh < 64) {
                gld_lds16(sp + (size_t)gh * 2048 + (seg * 64 + lane) * 8, dst);
            } else {
                *(int4*)(dst + (u32)lane * 16) = make_int4(0, 0, 0, 0);
            }
        }
    }
    __syncthreads();

    int m = lane & 15, g = lane >> 4;
    int wq = wid & 3, ocf = wid >> 2;
    int wbase = wq * 16;
    int oc = ocf * 16 + m;
    const bf16x8* FB1 = (const bf16x8*)fpack + (size_t)b * 1152;
    const bf16x8* FB2 = (const bf16x8*)fpack + (size_t)(NB + b) * 1152;

    // c1 passes: 3 rows, 8 waves cover 64px x 32oc per row
#pragma unroll
    for (int rr = 0; rr < 3; rr++) {
        int gh1 = row - 1 + rr;
        f32x4 acc = {0.f, 0.f, 0.f, 0.f};
#pragma unroll
        for (int t9 = 0; t9 < 9; t9++) {
            int dh = t9 / 3, dw = t9 - dh * 3;
            int wi = wbase + m + dw;
            bf16x8 a = *(const bf16x8*)(A + ((rr + dh) * 66 + wi) * 32
                                          + ((g ^ (wi & 3)) * 8));
            bf16x8 bb = FB1[(t9 * 2 + ocf) * 64 + lane];
            acc = __builtin_amdgcn_mfma_f32_16x16x32_bf16(a, bb, acc, 0, 0, 0);
        }
        if (gh1 >= 0 && gh1 < 64) {
#pragma unroll
            for (int r = 0; r < 4; r++) {
                float v = acc[r];
                v = (v >= 0.f) ? v : 0.2f * v;          // LeakyReLU
                int w = wbase + g * 4 + r;
                int wi2 = w + 1;
                int p = (((oc >> 3) ^ (wi2 & 3)) << 3) | (oc & 7);
                B[(rr * 66 + wi2) * 32 + p] = f2b(v);
            }
        }
    }
    __syncthreads();

    // c2 pass
    f32x4 acc = {0.f, 0.f, 0.f, 0.f};
#pragma unroll
    for (int t9 = 0; t9 < 9; t9++) {
        int dh = t9 / 3, dw = t9 - dh * 3;
        int wi = wbase + m + dw;
        bf16x8 a = *(const bf16x8*)(B + (dh * 66 + wi) * 32
                                      + ((g ^ (wi & 3)) * 8));
        bf16x8 bb = FB2[(t9 * 2 + ocf) * 64 + lane];
        acc = __builtin_amdgcn_mfma_f32_16x16x32_bf16(a, bb, acc, 0, 0, 0);
    }
    size_t obase = ((size_t)(b * 64 + row) * 64) * 32;
#pragma unroll
    for (int r = 0; r < 4; r++) {
        int w = wbase + g * 4 + r;
        int key = (w + 1) & 3;
        int p = (((oc >> 3) ^ key) << 3) | (oc & 7);
        c2T[obase + (size_t)w * 32 + p] = f2b(acc[r]);
    }
}

// ---------------------------------------------------------------------------
// Conv 32->512 (MFMA) + bias + residual -> out. blockIdx.y = oc quarter.
// LDS-bounced coalesced epilogue + early register prefetch of the residual.
// ---------------------------------------------------------------------------
__global__ __launch_bounds__(256) void k_conv_up(const u16* __restrict__ c2T,
        const u16* __restrict__ B2p, const void* __restrict__ upb,
        const void* __restrict__ content, void* __restrict__ outv, int hisf) {
    int isf32 = resolve_isf32(hisf, content);
    int b = blockIdx.x >> 6, row = blockIdx.x & 63;
    int nq = blockIdx.y;                           // 0..3
    int tid = threadIdx.x, lane = tid & 63;
    int wid = __builtin_amdgcn_readfirstlane(tid >> 6);
    __shared__ char smem[64 * 68 * 4] __attribute__((aligned(16)));  // 17408 B
    u16* lds = (u16*)smem;
    u32* lds32 = (u32*)smem;
    for (int i = tid; i < 96; i += 256) {
        int r = i >> 5, side = (i >> 4) & 1, cpr = i & 15;
        lds32[(r * 66 + side * 65) * 16 + cpr] = 0u;
    }
    const u16* sp = c2T + (size_t)b * 64 * 64 * 32;
    for (int r = 0; r < 3; r++) {
        int gh = row + r - 1;
        u32 ldsoff = (u32)(r * 66 + 1) * 64 + (u32)wid * 1024;
        if (gh >= 0 && gh < 64) {
            gld_lds16(sp + (size_t)gh * 2048 + tid * 8, (char*)lds + ldsoff);
        } else {
            int4 z = make_int4(0, 0, 0, 0);
            *(int4*)((char*)lds + ldsoff + (u32)lane * 16) = z;
        }
    }
    __syncthreads();

    int m = lane & 15, g = lane >> 4, wbase = wid * 16;
    f32x4 acc[8];
#pragma unroll
    for (int i = 0; i < 8; i++) acc[i] = (f32x4){0.f, 0.f, 0.f, 0.f};
#pragma unroll
    for (int t9 = 0; t9 < 9; t9++) {
        int dh = t9 / 3, dw = t9 - dh * 3;
        int wi = wbase + m + dw;
        bf16x8 a = *(const bf16x8*)(lds + ((dh * 66 + wi) * 32 + ((g ^ (wi & 3)) * 8)));
#pragma unroll
        for (int nfl = 0; nfl < 8; nfl++) {
            bf16x8 bw = ((const bf16x8*)B2p)[(t9 * 32 + nq * 8 + nfl) * 64 + lane];
            acc[nfl] = __builtin_amdgcn_mfma_f32_16x16x32_bf16(a, bw, acc[nfl], 0, 0, 0);
        }
    }

    // Coalesced epilogue via LDS: two halves of 64 oc, [ocl][px] stride 68.
    int pix0 = wbase + g * 4;
    float* fl = (float*)smem;
    int ocl2 = tid >> 4;            // 0..15
    int px0 = (tid & 15) * 4;       // 0..60
    __syncthreads();                // input tile dead

    if (isf32) {
        // prefetch residual into registers (independent of the LDS bounce)
        f32x4 rsd[2][4];
#pragma unroll
        for (int hf = 0; hf < 2; hf++)
#pragma unroll
            for (int p = 0; p < 4; p++) {
                int oc = nq * 128 + hf * 64 + p * 16 + ocl2;
                rsd[hf][p] = *(const f32x4*)((const float*)content
                    + ((size_t)b * NC + oc) * HW + (size_t)row * 64 + px0);
            }
#pragma unroll
        for (int hf = 0; hf < 2; hf++) {
            if (hf) __syncthreads();
#pragma unroll
            for (int nf = 0; nf < 4; nf++)
                *(f32x4*)(fl + (nf * 16 + m) * 68 + pix0) = acc[hf * 4 + nf];
            __syncthreads();
#pragma unroll
            for (int p = 0; p < 4; p++) {
                int oc = nq * 128 + hf * 64 + p * 16 + ocl2;
                float bias = ((const float*)upb)[oc];
                f32x4 v4 = *(const f32x4*)(fl + (p * 16 + ocl2) * 68 + px0);
                size_t idx = ((size_t)b * NC + oc) * HW + (size_t)row * 64 + px0;
                f32x4 ov;
#pragma unroll
                for (int r = 0; r < 4; r++) ov[r] = v4[r] + bias + rsd[hf][p][r];
                *(f32x4*)((float*)outv + idx) = ov;
            }
        }
    } else {
        ushort4 rsd[2][4];
#pragma unroll
        for (int hf = 0; hf < 2; hf++)
#pragma unroll
            for (int p = 0; p < 4; p++) {
                int oc = nq * 128 + hf * 64 + p * 16 + ocl2;
                rsd[hf][p] = *(const ushort4*)((const u16*)content
                    + ((size_t)b * NC + oc) * HW + (size_t)row * 64 + px0);
            }
#pragma unroll
        for (int hf = 0; hf < 2; hf++) {
            if (hf) __syncthreads();
#pragma unroll
            for (int nf = 0; nf < 4; nf++)
                *(f32x4*)(fl + (nf * 16 + m) * 68 + pix0) = acc[hf * 4 + nf];
            __syncthreads();
#pragma unroll
            for (int p = 0; p < 4; p++) {
                int oc = nq * 128 + hf * 64 + p * 16 + ocl2;
                float bias = b2f(((const u16*)upb)[oc]);
                f32x4 v4 = *(const f32x4*)(fl + (p * 16 + ocl2) * 68 + px0);
                size_t idx = ((size_t)b * NC + oc) * HW + (size_t)row * 64 + px0;
                ushort4 rv = rsd[hf][p];
                ushort4 ov;
                ov.x = f2b(v4[0] + bias + b2f(rv.x));
                ov.y = f2b(v4[1] + bias + b2f(rv.y));
                ov.z = f2b(v4[2] + bias + b2f(rv.z));
                ov.w = f2b(v4[3] + bias + b2f(rv.w));
                *(ushort4*)((u16*)outv + idx) = ov;
            }
        }
    }
}

// ---------------------------------------------------------------------------
extern "C" void kernel_launch(void* const* d_in, const int* in_sizes, int n_in,
                              void* d_out, int out_size, void* d_ws, size_t ws_size,
                              hipStream_t stream) {
    const void* content = d_in[0];
    const void* style   = d_in[1];
    const void* ds_w    = d_in[2];
    const void* ds_b    = d_in[3];
    const void* up_w    = d_in[4];
    const void* up_b    = d_in[5];
    const void* f1_cw   = d_in[6];
    const void* f1_cb   = d_in[7];
    const void* f1_fw   = d_in[8];
    const void* f1_fb   = d_in[9];
    const void* f2_cw   = d_in[10];
    const void* f2_cb   = d_in[11];
    const void* f2_fw   = d_in[12];
    const void* f2_fb   = d_in[13];

    // Host-side dtype resolution from exact input byte sizes; -1 = unknown,
    // kernels fall back to wave-ballot bit detection.
    int hisf = -1;
    if (in_sizes && n_in >= 1) {
        if (in_sizes[0] == NB * NC * HW * 4) hisf = 1;
        else if (in_sizes[0] == NB * NC * HW * 2) hisf = 0;
    }

    const size_t SZ_PACK = 294912;       // 147456 u16
    const size_t SZ_CT2  = 2097152;      // 1,048,576 u16 (32-ch bf16 tensor)
    const size_t REQ_WS  = 2 * SZ_CT2 + 3 * SZ_PACK + 2048 + 64;

    if (ws_size >= REQ_WS) {
        // FULL path: intermediates in d_ws; d_out holds only cT (full batch,
        // 33,554,432 B <= out_size), dead before k_conv_up writes out.
        char* w = (char*)d_ws;
        u16*   B2pack = (u16*)w;                 w += SZ_PACK;
        u16*   c2T    = (u16*)w;                 w += SZ_CT2;
        u16*   c0T    = (u16*)w;                 w += SZ_CT2;
        u16*   Bpack  = (u16*)w;                 w += SZ_PACK;
        u16*   fpack  = (u16*)w;                 w += SZ_PACK;
        float* pooled_raw = (float*)w;
        u16*   cT     = (u16*)d_out;

        hipMemsetAsync(pooled_raw, 0, 2 * NB * 32 * 4, stream);
        // L1: style(4096) + transform(4096, 2 rows/block) + preps(2x576)
        k_front<<<4096 + 4096 + 2 * 576, 256, 0, stream>>>(
            style, f1_cw, f2_cw, pooled_raw, 4096,
            content, cT, 0, 4096,
            ds_w, Bpack, up_w, B2pack, 576, hisf);
        // L2: conv_down(512, 8-wave) + fc(288, 512-thr)
        k_mid<<<512 + 288, 512, 0, stream>>>(
            cT, Bpack, ds_b, c0T, 0, 512,
            pooled_raw, f1_cb, f2_cb,
            f1_fw, f1_fb, f2_fw, f2_fb, fpack, content, hisf);
        // L3: fused dynamic convs
        k_apply2<<<NB * 64, 512, 0, stream>>>(c0T, fpack, c2T);
        // L4: conv_up
        k_conv_up<<<dim3(NB * 64, 4), 256, 0, stream>>>(c2T, B2pack, up_b,
                                                        content, d_out, hisf);
    } else {
        // HALF path (small ws): scratch in d_out, cT half-batch reused.
        float* pooled_raw = (float*)d_out;           //       512 f32
        u16*   fpack  = (u16*)(pooled_raw + 512);    //   147,456 u16
        u16*   Bpack  = fpack + 147456;              //   147,456 u16
        u16*   c0T    = Bpack + 147456;              // 1,048,576 u16
        u16*   cTh    = c0T + 1048576;               // 8,388,608 u16
        u16*   B2pack = (u16*)d_ws;                  //   147,456 u16
        u16*   c2T    = B2pack + 147456;             // 1,048,576 u16

        hipMemsetAsync(pooled_raw, 0, 2 * NB * 32 * 4, stream);
        // L1: style + transform(half0) + preps
        k_front<<<4096 + 2048 + 2 * 576, 256, 0, stream>>>(
            style, f1_cw, f2_cw, pooled_raw, 4096,
            content, cTh, 0, 2048,
            ds_w, Bpack, up_w, B2pack, 576, hisf);
        // L2: conv_down(half0) + fc
        k_mid<<<256 + 288, 512, 0, stream>>>(
            cTh, Bpack, ds_b, c0T, 0, 256,
            pooled_raw, f1_cb, f2_cb,
            f1_fw, f1_fb, f2_fw, f2_fb, fpack, content, hisf);
        // L3: transform(half1)
        k_front<<<2048, 256, 0, stream>>>(
            style, f1_cw, f2_cw, pooled_raw, 0,
            content, cTh, 4, 2048,
            ds_w, Bpack, up_w, B2pack, 0, hisf);
        // L4: conv_down(half1)
        k_mid<<<256, 512, 0, stream>>>(
            cTh, Bpack, ds_b, c0T, 4, 256,
            pooled_raw, f1_cb, f2_cb,
            f1_fw, f1_fb, f2_fw, f2_fb, fpack, content, hisf);
        // L5: fused dynamic convs
        k_apply2<<<NB * 64, 512, 0, stream>>>(c0T, fpack, c2T);
        // L6: conv_up
        k_conv_up<<<dim3(NB * 64, 4), 256, 0, stream>>>(c2T, B2pack, up_b,
                                                        content, d_out, hisf);
    }
}